// Round 1
// baseline (3747.225 us; speedup 1.0000x reference)
//
#include <hip/hip_runtime.h>
#include <cmath>

namespace {
constexpr int kB  = 16;
constexpr int kC  = 256;
constexpr int kH  = 96;
constexpr int kW  = 96;
constexpr int kNH = 8;
constexpr int kNG = 1024;   // 32*32 groups
constexpr float kScale = 0.17677669529663687f;  // 32^-0.5
}

// ---------------- k0: qkv of the (shared) group token: w_qkv(768x256) @ tok(256) ----------
__global__ void __launch_bounds__(256) k_tok(const float* __restrict__ w_qkv,
                                             const float* __restrict__ tok,
                                             float* __restrict__ out) {
  int o = blockIdx.x * 256 + threadIdx.x;   // grid 3*256 = 768
  const float4* wr = (const float4*)(w_qkv + (size_t)o * 256);
  const float4* tr = (const float4*)tok;
  float acc = 0.f;
#pragma unroll 8
  for (int i = 0; i < 64; ++i) {
    float4 w = wr[i], t = tr[i];
    acc += w.x * t.x + w.y * t.y + w.z * t.z + w.w * t.w;
  }
  out[o] = acc;
}

// ---------------- k1: fused qkv-GEMM + 10-token attention + LN + GELU (2 groups/block) ----
__global__ void __launch_bounds__(256, 2)
k_qkv_attn(const float* __restrict__ x, const float* __restrict__ w_qkv,
           const float* __restrict__ qkv_tok, const float* __restrict__ ln_g,
           const float* __restrict__ ln_b, float* __restrict__ t_ws,
           float* __restrict__ gf_ws) {
  __shared__ alignas(16) float xw[2][9][256];     // 18.4 KB, aliased by s_base in phase B
  __shared__ alignas(16) float qkv[2][10][769];   // 61.5 KB, [grp][token][o], stride 769
  int tid = threadIdx.x;
  int g0 = blockIdx.x * 2;
  int b = g0 >> 10;
  int n0 = g0 & 1023;

  // load the two 3x3 windows (c-major scatter; L2 absorbs line sharing with neighbors)
  for (int grp = 0; grp < 2; ++grp) {
    int n = n0 + grp;
    int gx = n >> 5, gy = n & 31;
    const float* xb = x + (size_t)b * kC * kH * kW;
    for (int i = tid; i < 9 * 256; i += 256) {
      int c = i & 255, pix = i >> 8;
      int gi = pix / 3, gj = pix % 3;
      xw[grp][pix][c] = xb[((size_t)c * kH + gx * 3 + gi) * kW + gy * 3 + gj];
    }
  }
  for (int o = tid; o < 768; o += 256) {
    float v = qkv_tok[o];
    qkv[0][0][o] = v;
    qkv[1][0][o] = v;
  }
  __syncthreads();

  // phase A: qkv for 18 pixel-columns, rows o = tid, tid+256, tid+512
  float acc[3][18];
#pragma unroll
  for (int r = 0; r < 3; ++r)
#pragma unroll
    for (int cl = 0; cl < 18; ++cl) acc[r][cl] = 0.f;
  const float4* w0 = (const float4*)(w_qkv + (size_t)tid * 256);
  const float4* w1 = (const float4*)(w_qkv + (size_t)(tid + 256) * 256);
  const float4* w2 = (const float4*)(w_qkv + (size_t)(tid + 512) * 256);
  for (int c4 = 0; c4 < 64; ++c4) {
    float4 a0 = w0[c4], a1 = w1[c4], a2 = w2[c4];
#pragma unroll
    for (int cl = 0; cl < 18; ++cl) {
      int grp = cl / 9, pix = cl % 9;
      float4 xv = *(const float4*)&xw[grp][pix][c4 * 4];
      acc[0][cl] += a0.x * xv.x + a0.y * xv.y + a0.z * xv.z + a0.w * xv.w;
      acc[1][cl] += a1.x * xv.x + a1.y * xv.y + a1.z * xv.z + a1.w * xv.w;
      acc[2][cl] += a2.x * xv.x + a2.y * xv.y + a2.z * xv.z + a2.w * xv.w;
    }
  }
#pragma unroll
  for (int r = 0; r < 3; ++r) {
    int o = tid + r * 256;
#pragma unroll
    for (int cl = 0; cl < 18; ++cl) {
      int grp = cl / 9, pix = cl % 9;
      qkv[grp][1 + pix][o] = acc[r][cl];
    }
  }
  __syncthreads();

  // phase B: per (group, head) 10x10 attention; 16 tasks over 4 waves x 2 halves x 2 iters
  float* s_base = &xw[0][0][0];   // xw is dead; reuse as score scratch: task*120 + i*12 + j
  int lane = tid & 63;
  int wv = tid >> 6;
  int sub = lane >> 5;
  int l32 = lane & 31;
  for (int it = 0; it < 2; ++it) {
    int task = wv * 4 + it * 2 + sub;
    int grp = task >> 3, hh = task & 7;
    const float* qk_g = &qkv[grp][0][0];
    // dots: 100 (i,j) pairs spread over the 32 lanes of each half-wave
#pragma unroll
    for (int di = 0; di < 4; ++di) {
      int idx = l32 + di * 32;
      if (idx < 100) {
        int i = idx / 10, j = idx - i * 10;
        const float* qp = qk_g + i * 769 + hh * 32;
        const float* kp = qk_g + j * 769 + 256 + hh * 32;
        float s = 0.f;
#pragma unroll
        for (int dd = 0; dd < 32; ++dd) s += qp[dd] * kp[dd];
        s_base[task * 120 + i * 12 + j] = s * kScale;
      }
    }
    __syncthreads();
    if (l32 < 10) {
      float* row = s_base + task * 120 + l32 * 12;
      float m = row[0];
#pragma unroll
      for (int j = 1; j < 10; ++j) m = fmaxf(m, row[j]);
      float sum = 0.f;
#pragma unroll
      for (int j = 0; j < 10; ++j) {
        float e = __expf(row[j] - m);
        row[j] = e;
        sum += e;
      }
      row[10] = 1.f / sum;
    }
    __syncthreads();
    // PV + LN/GELU + stores; lane = dd
    {
      int dd = l32;
      float vj[10];
#pragma unroll
      for (int j = 0; j < 10; ++j) vj[j] = qk_g[j * 769 + 512 + hh * 32 + dd];
      int n = n0 + grp;
      const float* prow = s_base + task * 120;
#pragma unroll
      for (int i = 0; i < 10; ++i) {
        float o = 0.f;
#pragma unroll
        for (int j = 0; j < 10; ++j) o += prow[i * 12 + j] * vj[j];
        o *= prow[i * 12 + 10];
        if (i == 0) {
          float s1 = o;
#pragma unroll
          for (int m = 1; m < 32; m <<= 1) s1 += __shfl_xor(s1, m, 64);
          float mu = s1 * (1.f / 32.f);
          float dv = o - mu;
          float s2 = dv * dv;
#pragma unroll
          for (int m = 1; m < 32; m <<= 1) s2 += __shfl_xor(s2, m, 64);
          float var = s2 * (1.f / 32.f);
          float gtn = dv * rsqrtf(var + 1e-5f) * ln_g[dd] + ln_b[dd];
          float ge = 0.5f * gtn * (1.f + erff(gtn * 0.70710678118654752f));
          t_ws[((size_t)b * kNG + n) * 256 + hh * 32 + dd] = ge;
        } else {
          gf_ws[(((size_t)b * kNH + hh) * kNG + n) * 288 + (i - 1) * 32 + dd] = o;
        }
      }
    }
    __syncthreads();
  }
}

// ---------------- k2: qk = w_qk(512x256) @ t + b_qk, scattered to wq/wk (B,8,1024,32) ----
__global__ void __launch_bounds__(256, 2)
k_qk(const float* __restrict__ t_ws, const float* __restrict__ w_qk,
     const float* __restrict__ b_qk, float* __restrict__ wq, float* __restrict__ wk) {
  __shared__ float t_l[128][33];
  __shared__ float w_l[64][33];
  int tid = threadIdx.x;
  int bid = blockIdx.x;       // 16 b * 8 h * 8 ntiles
  int b = bid >> 6;
  int h = (bid >> 3) & 7;
  int nt = bid & 7;
  int n_base = nt * 128;
  int te = tid & 15, tn = tid >> 4;
  float accq[4][8] = {};
  for (int c0 = 0; c0 < 256; c0 += 32) {
    for (int i = 0; i < 16; ++i) {
      int nl = i * 8 + (tid >> 5);
      t_l[nl][tid & 31] = t_ws[((size_t)b * kNG + n_base + nl) * 256 + c0 + (tid & 31)];
    }
    for (int i = 0; i < 8; ++i) {
      int e = i * 8 + (tid >> 5);
      w_l[e][tid & 31] = w_qk[(size_t)(h * 64 + e) * 256 + c0 + (tid & 31)];
    }
    __syncthreads();
    for (int cc = 0; cc < 32; ++cc) {
      float wvv[4], tvv[8];
#pragma unroll
      for (int i = 0; i < 4; ++i) wvv[i] = w_l[te + 16 * i][cc];
#pragma unroll
      for (int j = 0; j < 8; ++j) tvv[j] = t_l[tn + 16 * j][cc];
#pragma unroll
      for (int i = 0; i < 4; ++i)
#pragma unroll
        for (int j = 0; j < 8; ++j) accq[i][j] += wvv[i] * tvv[j];
    }
    __syncthreads();
  }
#pragma unroll
  for (int i = 0; i < 4; ++i) {
    int e = te + 16 * i;
    float bias = b_qk[h * 64 + e];
#pragma unroll
    for (int j = 0; j < 8; ++j) {
      int n = n_base + tn + 16 * j;
      float v = accq[i][j] + bias;
      if (e < 32)
        wq[(((size_t)b * kNH + h) * kNG + n) * 32 + e] = v;
      else
        wk[(((size_t)b * kNH + h) * kNG + n) * 32 + (e - 32)] = v;
    }
  }
}

// ---------------- k3: flash attention over 1024 groups, V = gf (288 cols) ----------------
__global__ void __launch_bounds__(256, 2)
k_flash(const float* __restrict__ wq, const float* __restrict__ wk,
        const float* __restrict__ gf, float* __restrict__ agg) {
  __shared__ alignas(16) float q_l[64][36];
  __shared__ alignas(16) float k_l[32][36];
  __shared__ alignas(16) float v_l[32 * 288];
  __shared__ float p_l[32 * 65];
  int tid = threadIdx.x;
  int bid = blockIdx.x;       // 16 b * 8 h * 16 qtiles
  int b = bid >> 7;
  int h = (bid >> 4) & 7;
  int qt = bid & 15;
  int tx = tid & 31, ty = tid >> 5;
  size_t bh = (size_t)b * kNH + h;

  for (int it = 0; it < 2; ++it) {
    int idx = tid + it * 256;
    int row = idx >> 3, d4 = idx & 7;
    float4 qv = *(const float4*)&wq[(bh * kNG + qt * 64 + row) * 32 + d4 * 4];
    qv.x *= kScale; qv.y *= kScale; qv.z *= kScale; qv.w *= kScale;
    *(float4*)&q_l[row][d4 * 4] = qv;
  }
  float accv[8][9];
#pragma unroll
  for (int r = 0; r < 8; ++r)
#pragma unroll
    for (int c = 0; c < 9; ++c) accv[r][c] = 0.f;
  float m_r[8], l_r[8];
#pragma unroll
  for (int r = 0; r < 8; ++r) { m_r[r] = -INFINITY; l_r[r] = 0.f; }

  for (int kt = 0; kt < 32; ++kt) {
    {
      int row = tid >> 3, d4 = tid & 7;
      *(float4*)&k_l[row][d4 * 4] =
          *(const float4*)&wk[(bh * kNG + kt * 32 + row) * 32 + d4 * 4];
    }
#pragma unroll
    for (int i = 0; i < 9; ++i) {
      int idx = tid + i * 256;            // v_l float index = 4*idx (288 = 72*4)
      *(float4*)&v_l[idx * 4] =
          *(const float4*)&gf[(bh * kNG + kt * 32) * 288 + idx * 4];
    }
    __syncthreads();
    float4 kreg[8];
#pragma unroll
    for (int d4 = 0; d4 < 8; ++d4) kreg[d4] = *(const float4*)&k_l[tx][d4 * 4];
    float sv[8];
#pragma unroll
    for (int rr = 0; rr < 8; ++rr) {
      const float* qrow = q_l[ty * 8 + rr];
      float s = 0.f;
#pragma unroll
      for (int d4 = 0; d4 < 8; ++d4) {
        float4 qv = *(const float4*)&qrow[d4 * 4];
        s += qv.x * kreg[d4].x + qv.y * kreg[d4].y + qv.z * kreg[d4].z + qv.w * kreg[d4].w;
      }
      sv[rr] = s;
    }
#pragma unroll
    for (int rr = 0; rr < 8; ++rr) {
      float mt = sv[rr];
#pragma unroll
      for (int m = 1; m < 32; m <<= 1) mt = fmaxf(mt, __shfl_xor(mt, m, 64));
      float mn = fmaxf(m_r[rr], mt);
      float alpha = __expf(m_r[rr] - mn);
      float p = __expf(sv[rr] - mn);
      float ps = p;
#pragma unroll
      for (int m = 1; m < 32; m <<= 1) ps += __shfl_xor(ps, m, 64);
      l_r[rr] = l_r[rr] * alpha + ps;
      m_r[rr] = mn;
#pragma unroll
      for (int cc = 0; cc < 9; ++cc) accv[rr][cc] *= alpha;
      p_l[tx * 65 + ty * 8 + rr] = p;
    }
    __syncthreads();
    for (int j = 0; j < 32; ++j) {
      float pj[8];
#pragma unroll
      for (int rr = 0; rr < 8; ++rr) pj[rr] = p_l[j * 65 + ty * 8 + rr];
      float vvv[9];
#pragma unroll
      for (int cc = 0; cc < 9; ++cc) vvv[cc] = v_l[j * 288 + tx * 9 + cc];
#pragma unroll
      for (int rr = 0; rr < 8; ++rr)
#pragma unroll
        for (int cc = 0; cc < 9; ++cc) accv[rr][cc] += pj[rr] * vvv[cc];
    }
    __syncthreads();
  }
#pragma unroll
  for (int rr = 0; rr < 8; ++rr) {
    float rinv = 1.f / l_r[rr];
    size_t base = (bh * kNG + qt * 64 + ty * 8 + rr) * 288 + tx * 9;
#pragma unroll
    for (int cc = 0; cc < 9; ++cc) agg[base + cc] = accv[rr][cc] * rinv;
  }
}

// ---------------- k4: out = w_out(256x256) @ fmap(gathered from agg) + b_out -------------
__global__ void __launch_bounds__(256, 2)
k_out(const float* __restrict__ agg, const float* __restrict__ w_out,
      const float* __restrict__ b_out, float* __restrict__ out) {
  __shared__ float fm[64][33];
  __shared__ float wl[256][33];
  int tid = threadIdx.x;
  int bid = blockIdx.x;       // 16 b * 144 ptiles
  int b = bid / 144;
  int pt = bid - b * 144;
  int p_base = pt * 64;
  int tp = tid & 15, to = tid >> 4;
  float acco[16][4] = {};
  for (int h = 0; h < 8; ++h) {
#pragma unroll
    for (int ii = 0; ii < 8; ++ii) {
      int pix = ii * 8 + (tid >> 5);
      int dd = tid & 31;
      int p = p_base + pix;
      int hh2 = p / 96, ww2 = p - hh2 * 96;
      int xg = hh2 / 3, gi = hh2 - xg * 3;
      int yg = ww2 / 3, gj = ww2 - yg * 3;
      int n = xg * 32 + yg, w = gi * 3 + gj;
      fm[pix][dd] = agg[(((size_t)b * kNH + h) * kNG + n) * 288 + w * 32 + dd];
    }
#pragma unroll
    for (int ii = 0; ii < 32; ++ii) {
      int o = ii * 8 + (tid >> 5);
      int dd = tid & 31;
      wl[o][dd] = w_out[(size_t)o * 256 + h * 32 + dd];
    }
    __syncthreads();
    for (int cc = 0; cc < 32; ++cc) {
      float fv[4], wvv[16];
#pragma unroll
      for (int j = 0; j < 4; ++j) fv[j] = fm[tp + 16 * j][cc];
#pragma unroll
      for (int i = 0; i < 16; ++i) wvv[i] = wl[to + 16 * i][cc];
#pragma unroll
      for (int i = 0; i < 16; ++i)
#pragma unroll
        for (int j = 0; j < 4; ++j) acco[i][j] += wvv[i] * fv[j];
    }
    __syncthreads();
  }
#pragma unroll
  for (int i = 0; i < 16; ++i) {
    int o = to + 16 * i;
    float bias = b_out[o];
#pragma unroll
    for (int j = 0; j < 4; ++j) {
      int p = p_base + tp + 16 * j;
      out[((size_t)b * 256 + o) * 9216 + p] = acco[i][j] + bias;
    }
  }
}

extern "C" void kernel_launch(void* const* d_in, const int* in_sizes, int n_in,
                              void* d_out, int out_size, void* d_ws, size_t ws_size,
                              hipStream_t stream) {
  const float* x     = (const float*)d_in[0];
  const float* w_qkv = (const float*)d_in[1];
  const float* gtok  = (const float*)d_in[2];
  const float* ln_g  = (const float*)d_in[3];
  const float* ln_b  = (const float*)d_in[4];
  const float* w_qk  = (const float*)d_in[5];
  const float* b_qk  = (const float*)d_in[6];
  const float* w_out = (const float*)d_in[7];
  const float* b_out = (const float*)d_in[8];
  float* out = (float*)d_out;

  float* ws  = (float*)d_ws;
  float* tok  = ws;                      // 768 (pad to 1024)
  float* t_ws = ws + 1024;               // 16*1024*256      = 4,194,304
  float* wq   = t_ws + 4194304;          // 16*8*1024*32     = 4,194,304
  float* wk   = wq + 4194304;            // 4,194,304
  float* gf   = wk + 4194304;            // 16*8*1024*288    = 37,748,736
  float* agg  = gf + 37748736;           // 37,748,736
  // total ~88.1M floats = 352 MB

  k_tok<<<3, 256, 0, stream>>>(w_qkv, gtok, tok);
  k_qkv_attn<<<8192, 256, 0, stream>>>(x, w_qkv, tok, ln_g, ln_b, t_ws, gf);
  k_qk<<<1024, 256, 0, stream>>>(t_ws, w_qk, b_qk, wq, wk);
  k_flash<<<2048, 256, 0, stream>>>(wq, wk, gf, agg);
  k_out<<<2304, 256, 0, stream>>>(agg, w_out, b_out, out);
}

// Round 2
// 2510.768 us; speedup vs baseline: 1.4925x; 1.4925x over previous
//
#include <hip/hip_runtime.h>
#include <cmath>

namespace {
constexpr int kB  = 16;
constexpr int kNH = 8;
constexpr int kNG = 1024;   // 32*32 groups
constexpr float kScale = 0.17677669529663687f;  // 32^-0.5
}

typedef short  bf16x8 __attribute__((ext_vector_type(8)));
typedef short  bf16x4 __attribute__((ext_vector_type(4)));
typedef float  f32x4  __attribute__((ext_vector_type(4)));

__device__ __forceinline__ unsigned short f2b(float f) {
  unsigned int u = __builtin_bit_cast(unsigned int, f);
  u += 0x7fffu + ((u >> 16) & 1u);          // RNE
  return (unsigned short)(u >> 16);
}
__device__ __forceinline__ float b2f(unsigned short h) {
  unsigned int u = ((unsigned int)h) << 16;
  return __builtin_bit_cast(float, u);
}

// ---------------- k_wcvt: w_qkv (768x256) fp32 -> bf16 ----------------
__global__ void __launch_bounds__(256) k_wcvt(const float* __restrict__ w,
                                              unsigned short* __restrict__ wb) {
  int i = blockIdx.x * 256 + threadIdx.x;   // grid 768 -> 196608
  wb[i] = f2b(w[i]);
}

// ---------------- k1: fused MFMA qkv-GEMM + 10-token attention + LN/GELU --------
// Block: 2 groups. GEMM D[m=32 token-rows (2 grps x 16)][n=768 o] = Xg * W^T, K=256.
// m-row layout per group: 0 = group token, 1..9 = pixels, 10..15 = zero (masked).
// LDS (shorts): qk_l[32][520] (aliased by A_l[32][264] in phase 1),
//               vt[2*256][40] (V^T, j-slots 16..31 zeroed), pl[4][16][40].
__global__ void __launch_bounds__(256, 2)
k_qkv_attn(const float* __restrict__ x, const unsigned short* __restrict__ w_bf,
           const float* __restrict__ gtok, const float* __restrict__ ln_g,
           const float* __restrict__ ln_b, unsigned short* __restrict__ t_b,
           unsigned short* __restrict__ gf_b) {
  __shared__ __align__(16) short smem[39680];   // 79360 B
  short* qk_l = smem;            // [32][520]   (phase2) / A_l [32][264] (phase1)
  short* vt   = smem + 16640;    // [512][40]
  short* pl   = smem + 37120;    // [4][16][40]

  const int tid = threadIdx.x;
  const int bid = blockIdx.x;            // 16 b * 512 pairs
  const int b   = bid >> 9;
  const int n0  = (bid & 511) * 2;
  const int wv  = tid >> 6;
  const int lane = tid & 63;
  const int ln  = lane & 15;
  const int qq  = lane >> 4;
  const int n0w = wv * 192;

  // ---- stage A (gathered x window + token row, zero pad rows) ----
  for (int r = 0; r < 32; ++r) {
    int i = r * 256 + tid;
    int m = i & 31, c = i >> 5;
    int m16 = m & 15;
    float val = 0.f;
    if (m16 == 0) {
      val = gtok[c];
    } else if (m16 <= 9) {
      int pix = m16 - 1;
      int n = n0 + (m >> 4);
      int gx = n >> 5, gy = n & 31;
      int gi = pix / 3, gj = pix - gi * 3;
      val = x[((size_t)(b * 256 + c) * 96 + gx * 3 + gi) * 96 + gy * 3 + gj];
    }
    qk_l[m * 264 + c] = (short)f2b(val);   // A_l alias
  }
  __syncthreads();

  // ---- K-loop: D[m][o] = sum_c A[m][c] * W[o][c] ----
  f32x4 acc[2][12];
#pragma unroll
  for (int mf = 0; mf < 2; ++mf)
#pragma unroll
    for (int nf = 0; nf < 12; ++nf) acc[mf][nf] = {0.f, 0.f, 0.f, 0.f};

  for (int ks = 0; ks < 8; ++ks) {
    bf16x8 a0 = *(const bf16x8*)&qk_l[ln * 264 + ks * 32 + qq * 8];
    bf16x8 a1 = *(const bf16x8*)&qk_l[(16 + ln) * 264 + ks * 32 + qq * 8];
#pragma unroll
    for (int nf = 0; nf < 12; ++nf) {
      bf16x8 bw = *(const bf16x8*)&w_bf[(size_t)(n0w + nf * 16 + ln) * 256 + ks * 32 + qq * 8];
      acc[0][nf] = __builtin_amdgcn_mfma_f32_16x16x32_bf16(a0, bw, acc[0][nf], 0, 0, 0);
      acc[1][nf] = __builtin_amdgcn_mfma_f32_16x16x32_bf16(a1, bw, acc[1][nf], 0, 0, 0);
    }
  }
  __syncthreads();   // A_l dead

  // ---- scatter D -> qk_l (q,k) and vt (v transposed), plus zero pads ----
#pragma unroll
  for (int mf = 0; mf < 2; ++mf)
#pragma unroll
    for (int nf = 0; nf < 12; ++nf) {
      int o = n0w + nf * 16 + ln;
#pragma unroll
      for (int r = 0; r < 4; ++r) {
        short hv = (short)f2b(acc[mf][nf][r]);
        int ml = qq * 4 + r;
        if (o < 512) qk_l[(mf * 16 + ml) * 520 + o] = hv;
        else         vt[((mf << 8) + (o - 512)) * 40 + ml] = hv;
      }
    }
  for (int t = tid; t < 8192; t += 256) vt[(t >> 4) * 40 + 16 + (t & 15)] = 0;
  for (int t = tid; t < 1024; t += 256)
    pl[(t >> 8) * 640 + ((t & 255) >> 4) * 40 + 16 + (t & 15)] = 0;
  __syncthreads();

  // ---- per (group, head) attention: 4 tasks per wave ----
  for (int tt = 0; tt < 4; ++tt) {
    int task = wv * 4 + tt;
    int grp = task >> 3, hh = task & 7;
    int n = n0 + grp;

    bf16x8 aq = *(const bf16x8*)&qk_l[(grp * 16 + ln) * 520 + hh * 32 + qq * 8];
    bf16x8 bk = *(const bf16x8*)&qk_l[(grp * 16 + ln) * 520 + 256 + hh * 32 + qq * 8];
    f32x4 z = {0.f, 0.f, 0.f, 0.f};
    f32x4 s = __builtin_amdgcn_mfma_f32_16x16x32_bf16(aq, bk, z, 0, 0, 0);

    float pr[4], sm[4];
#pragma unroll
    for (int r = 0; r < 4; ++r) {
      float sv = s[r] * kScale;
      if (ln >= 10) sv = -1e30f;
      float mx = sv;
#pragma unroll
      for (int d = 1; d < 16; d <<= 1) mx = fmaxf(mx, __shfl_xor(mx, d));
      pr[r] = __expf(sv - mx);
      float t2 = pr[r];
#pragma unroll
      for (int d = 1; d < 16; d <<= 1) t2 += __shfl_xor(t2, d);
      sm[r] = t2;
    }
#pragma unroll
    for (int r = 0; r < 4; ++r)
      pl[wv * 640 + (qq * 4 + r) * 40 + ln] = (short)f2b(pr[r]);

    bf16x8 ap = *(const bf16x8*)&pl[wv * 640 + ln * 40 + qq * 8];
    bf16x8 v0 = *(const bf16x8*)&vt[((grp << 8) + hh * 32 + ln) * 40 + qq * 8];
    bf16x8 v1 = *(const bf16x8*)&vt[((grp << 8) + hh * 32 + 16 + ln) * 40 + qq * 8];
    f32x4 o0 = __builtin_amdgcn_mfma_f32_16x16x32_bf16(ap, v0, z, 0, 0, 0);
    f32x4 o1 = __builtin_amdgcn_mfma_f32_16x16x32_bf16(ap, v1, z, 0, 0, 0);

    if (qq == 0) {  // row 0 = group token -> LN + GELU -> t
      float inv0 = 1.f / sm[0];
      float va = o0[0] * inv0, vb = o1[0] * inv0;
      float ssum = va + vb;
#pragma unroll
      for (int d = 1; d < 16; d <<= 1) ssum += __shfl_xor(ssum, d);
      float mu = ssum * (1.f / 32.f);
      float dva = va - mu, dvb = vb - mu;
      float vsum = dva * dva + dvb * dvb;
#pragma unroll
      for (int d = 1; d < 16; d <<= 1) vsum += __shfl_xor(vsum, d);
      float ri = rsqrtf(vsum * (1.f / 32.f) + 1e-5f);
      float g0 = dva * ri * ln_g[ln] + ln_b[ln];
      float g1 = dvb * ri * ln_g[16 + ln] + ln_b[16 + ln];
      float e0 = 0.5f * g0 * (1.f + erff(g0 * 0.70710678118654752f));
      float e1 = 0.5f * g1 * (1.f + erff(g1 * 0.70710678118654752f));
      size_t tb = ((size_t)(b * 1024 + n)) * 256 + hh * 32 + ln;
      t_b[tb] = f2b(e0);
      t_b[tb + 16] = f2b(e1);
    }
#pragma unroll
    for (int r = 0; r < 4; ++r) {
      int i = qq * 4 + r;
      if (i >= 1 && i <= 9) {
        float inv = 1.f / sm[r];
        size_t base = ((size_t)((b * 8 + hh) * 1024) + n) * 288 + (i - 1) * 32 + ln;
        gf_b[base] = f2b(o0[r] * inv);
        gf_b[base + 16] = f2b(o1[r] * inv);
      }
    }
  }
}

// ---------------- k2: qk = w_qk(512x256) @ t + b_qk -> wq_b (scaled), wk_b ------
__global__ void __launch_bounds__(256, 2)
k_qk(const unsigned short* __restrict__ t_b, const float* __restrict__ w_qk,
     const float* __restrict__ b_qk, unsigned short* __restrict__ wq_b,
     unsigned short* __restrict__ wk_b) {
  __shared__ float t_l[128][33];
  __shared__ float w_l[64][33];
  int tid = threadIdx.x;
  int bid = blockIdx.x;       // 16 b * 8 h * 8 ntiles
  int b = bid >> 6;
  int h = (bid >> 3) & 7;
  int nt = bid & 7;
  int n_base = nt * 128;
  int te = tid & 15, tn = tid >> 4;
  float accq[4][8] = {};
  for (int c0 = 0; c0 < 256; c0 += 32) {
    for (int i = 0; i < 16; ++i) {
      int nl = i * 8 + (tid >> 5);
      t_l[nl][tid & 31] = b2f(t_b[((size_t)(b * kNG) + n_base + nl) * 256 + c0 + (tid & 31)]);
    }
    for (int i = 0; i < 8; ++i) {
      int e = i * 8 + (tid >> 5);
      w_l[e][tid & 31] = w_qk[(size_t)(h * 64 + e) * 256 + c0 + (tid & 31)];
    }
    __syncthreads();
    for (int cc = 0; cc < 32; ++cc) {
      float wvv[4], tvv[8];
#pragma unroll
      for (int i = 0; i < 4; ++i) wvv[i] = w_l[te + 16 * i][cc];
#pragma unroll
      for (int j = 0; j < 8; ++j) tvv[j] = t_l[tn + 16 * j][cc];
#pragma unroll
      for (int i = 0; i < 4; ++i)
#pragma unroll
        for (int j = 0; j < 8; ++j) accq[i][j] += wvv[i] * tvv[j];
    }
    __syncthreads();
  }
#pragma unroll
  for (int i = 0; i < 4; ++i) {
    int e = te + 16 * i;
    float bias = b_qk[h * 64 + e];
#pragma unroll
    for (int j = 0; j < 8; ++j) {
      int n = n_base + tn + 16 * j;
      float v = accq[i][j] + bias;
      size_t idx = (((size_t)b * kNH + h) * kNG + n) * 32;
      if (e < 32) wq_b[idx + e] = f2b(v * kScale);
      else        wk_b[idx + (e - 32)] = f2b(v);
    }
  }
}

// ---------------- k3: MFMA flash attention, V = gf (288 cols), agg bf16 ---------
// Block: (bh, 64-row q-tile). Waves replicate QK/softmax, split 288 d-cols (80 each).
__global__ void __launch_bounds__(256, 2)
k_flash(const unsigned short* __restrict__ wq_b, const unsigned short* __restrict__ wk_b,
        const unsigned short* __restrict__ gf_b, unsigned short* __restrict__ agg_b) {
  __shared__ __align__(16) short smem[24320];
  short* k_l = smem;             // [32][40]
  short* vt  = smem + 1280;      // [320][40]  (rows >=288 garbage, cols masked at store)
  short* pl  = smem + 14080;     // [4][64][40]

  const int tid = threadIdx.x;
  const int bid = blockIdx.x;    // 128 bh * 16 qtiles
  const int bh = bid >> 4;
  const int qt = bid & 15;
  const int wv = tid >> 6;
  const int lane = tid & 63;
  const int ln = lane & 15;
  const int qq = lane >> 4;
  const int d0 = wv * 80;

  bf16x8 aq[4];
#pragma unroll
  for (int mf = 0; mf < 4; ++mf)
    aq[mf] = *(const bf16x8*)&wq_b[(size_t)(bh * 1024 + qt * 64 + mf * 16 + ln) * 32 + qq * 8];

  f32x4 accv[4][5];
  float mrow[4][4], lrow[4][4];
#pragma unroll
  for (int mf = 0; mf < 4; ++mf) {
#pragma unroll
    for (int nf = 0; nf < 5; ++nf) accv[mf][nf] = {0.f, 0.f, 0.f, 0.f};
#pragma unroll
    for (int r = 0; r < 4; ++r) { mrow[mf][r] = -1e30f; lrow[mf][r] = 0.f; }
  }

  for (int kt = 0; kt < 32; ++kt) {
    { // stage K tile [32 kc][32 d]
      int kc = tid >> 3, dd = (tid & 7) * 4;
      bf16x4 kv = *(const bf16x4*)&wk_b[(size_t)(bh * 1024 + kt * 32 + kc) * 32 + dd];
      *(bf16x4*)&k_l[kc * 40 + dd] = kv;
    }
#pragma unroll
    for (int r = 0; r < 9; ++r) {  // stage V^T: vt[d][kc]
      int i = r * 256 + tid;
      int kc = i / 72, jj = i - kc * 72;
      int d4 = jj * 4;
      bf16x4 g4 = *(const bf16x4*)&gf_b[(size_t)(bh * 1024 + kt * 32 + kc) * 288 + d4];
#pragma unroll
      for (int xch = 0; xch < 4; ++xch) vt[(d4 + xch) * 40 + kc] = g4[xch];
    }
    __syncthreads();

    // QK
    f32x4 s[4][2];
    f32x4 z = {0.f, 0.f, 0.f, 0.f};
#pragma unroll
    for (int nf2 = 0; nf2 < 2; ++nf2) {
      bf16x8 kf = *(const bf16x8*)&k_l[(nf2 * 16 + ln) * 40 + qq * 8];
#pragma unroll
      for (int mf = 0; mf < 4; ++mf)
        s[mf][nf2] = __builtin_amdgcn_mfma_f32_16x16x32_bf16(aq[mf], kf, z, 0, 0, 0);
    }
    // online softmax per row
#pragma unroll
    for (int mf = 0; mf < 4; ++mf)
#pragma unroll
      for (int r = 0; r < 4; ++r) {
        float s0 = s[mf][0][r], s1 = s[mf][1][r];
        float tm = fmaxf(s0, s1);
#pragma unroll
        for (int d = 1; d < 16; d <<= 1) tm = fmaxf(tm, __shfl_xor(tm, d));
        float nm = fmaxf(mrow[mf][r], tm);
        float al = __expf(mrow[mf][r] - nm);
        mrow[mf][r] = nm;
        float p0 = __expf(s0 - nm), p1 = __expf(s1 - nm);
        float ts = p0 + p1;
#pragma unroll
        for (int d = 1; d < 16; d <<= 1) ts += __shfl_xor(ts, d);
        lrow[mf][r] = lrow[mf][r] * al + ts;
#pragma unroll
        for (int nf = 0; nf < 5; ++nf) accv[mf][nf][r] *= al;
        int row = mf * 16 + qq * 4 + r;
        pl[wv * 2560 + row * 40 + ln] = (short)f2b(p0);
        pl[wv * 2560 + row * 40 + 16 + ln] = (short)f2b(p1);
      }
    // PV
    bf16x8 ap[4];
#pragma unroll
    for (int mf = 0; mf < 4; ++mf)
      ap[mf] = *(const bf16x8*)&pl[wv * 2560 + (mf * 16 + ln) * 40 + qq * 8];
#pragma unroll
    for (int nf = 0; nf < 5; ++nf) {
      bf16x8 vf = *(const bf16x8*)&vt[(d0 + nf * 16 + ln) * 40 + qq * 8];
#pragma unroll
      for (int mf = 0; mf < 4; ++mf)
        accv[mf][nf] = __builtin_amdgcn_mfma_f32_16x16x32_bf16(ap[mf], vf, accv[mf][nf], 0, 0, 0);
    }
    __syncthreads();
  }
  // epilogue
#pragma unroll
  for (int mf = 0; mf < 4; ++mf)
#pragma unroll
    for (int nf = 0; nf < 5; ++nf) {
      int d = d0 + nf * 16 + ln;
      if (d < 288) {
#pragma unroll
        for (int r = 0; r < 4; ++r) {
          int row = qt * 64 + mf * 16 + qq * 4 + r;
          agg_b[((size_t)(bh * 1024) + row) * 288 + d] = f2b(accv[mf][nf][r] / lrow[mf][r]);
        }
      }
    }
}

// ---------------- k4: out = w_out(256x256) @ fmap(gathered from agg bf16) + b_out ----
__global__ void __launch_bounds__(256, 2)
k_out(const unsigned short* __restrict__ agg_b, const float* __restrict__ w_out,
      const float* __restrict__ b_out, float* __restrict__ out) {
  __shared__ float fm[64][33];
  __shared__ float wl[256][33];
  int tid = threadIdx.x;
  int bid = blockIdx.x;       // 16 b * 144 ptiles
  int b = bid / 144;
  int pt = bid - b * 144;
  int p_base = pt * 64;
  int tp = tid & 15, to = tid >> 4;
  float acco[16][4] = {};
  for (int h = 0; h < 8; ++h) {
#pragma unroll
    for (int ii = 0; ii < 8; ++ii) {
      int pix = ii * 8 + (tid >> 5);
      int dd = tid & 31;
      int p = p_base + pix;
      int hh2 = p / 96, ww2 = p - hh2 * 96;
      int xg = hh2 / 3, gi = hh2 - xg * 3;
      int yg = ww2 / 3, gj = ww2 - yg * 3;
      int n = xg * 32 + yg, w = gi * 3 + gj;
      fm[pix][dd] = b2f(agg_b[(((size_t)b * kNH + h) * kNG + n) * 288 + w * 32 + dd]);
    }
#pragma unroll
    for (int ii = 0; ii < 32; ++ii) {
      int o = ii * 8 + (tid >> 5);
      int dd = tid & 31;
      wl[o][dd] = w_out[(size_t)o * 256 + h * 32 + dd];
    }
    __syncthreads();
    for (int cc = 0; cc < 32; ++cc) {
      float fv[4], wvv[16];
#pragma unroll
      for (int j = 0; j < 4; ++j) fv[j] = fm[tp + 16 * j][cc];
#pragma unroll
      for (int i = 0; i < 16; ++i) wvv[i] = wl[to + 16 * i][cc];
#pragma unroll
      for (int i = 0; i < 16; ++i)
#pragma unroll
        for (int j = 0; j < 4; ++j) acco[i][j] += wvv[i] * fv[j];
    }
    __syncthreads();
  }
#pragma unroll
  for (int i = 0; i < 16; ++i) {
    int o = to + 16 * i;
    float bias = b_out[o];
#pragma unroll
    for (int j = 0; j < 4; ++j) {
      int p = p_base + tp + 16 * j;
      out[((size_t)b * 256 + o) * 9216 + p] = acco[i][j] + bias;
    }
  }
}

extern "C" void kernel_launch(void* const* d_in, const int* in_sizes, int n_in,
                              void* d_out, int out_size, void* d_ws, size_t ws_size,
                              hipStream_t stream) {
  const float* x     = (const float*)d_in[0];
  const float* w_qkv = (const float*)d_in[1];
  const float* gtok  = (const float*)d_in[2];
  const float* ln_g  = (const float*)d_in[3];
  const float* ln_b  = (const float*)d_in[4];
  const float* w_qk  = (const float*)d_in[5];
  const float* b_qk  = (const float*)d_in[6];
  const float* w_out = (const float*)d_in[7];
  const float* b_out = (const float*)d_in[8];
  float* out = (float*)d_out;

  unsigned short* ws   = (unsigned short*)d_ws;
  unsigned short* w_bf = ws;                        // 196,608
  unsigned short* t_b  = w_bf + 196608;             // 16*1024*256   = 4,194,304
  unsigned short* wq_b = t_b + 4194304;             // 16*8*1024*32  = 4,194,304
  unsigned short* wk_b = wq_b + 4194304;            // 4,194,304
  unsigned short* gf_b = wk_b + 4194304;            // 16*8*1024*288 = 37,748,736
  unsigned short* agg_b = gf_b + 37748736;          // 37,748,736
  // total ~88.3M shorts = 176.5 MB

  k_wcvt<<<768, 256, 0, stream>>>(w_qkv, w_bf);
  k_qkv_attn<<<8192, 256, 0, stream>>>(x, w_bf, gtok, ln_g, ln_b, t_b, gf_b);
  k_qk<<<1024, 256, 0, stream>>>(t_b, w_qk, b_qk, wq_b, wk_b);
  k_flash<<<2048, 256, 0, stream>>>(wq_b, wk_b, gf_b, agg_b);
  k_out<<<2304, 256, 0, stream>>>(agg_b, w_out, b_out, out);
}